// Round 1
// baseline (27248.343 us; speedup 1.0000x reference)
//
#include <hip/hip_runtime.h>
#include <math.h>

#define BATCHN 32
#define SEQT   2048
#define NMELS  80
#define HIDN   512
#define NCLSN  64
#define BTROWS (BATCHN*SEQT)   // 65536

typedef unsigned long long u64;

__device__ inline float wave_sum(float v) {
  #pragma unroll
  for (int o = 32; o > 0; o >>= 1) v += __shfl_xor(v, o, 64);
  return v;
}
__device__ inline float ftanh(float x) {
  float ax = fabsf(x);
  float e = __expf(2.0f*ax);
  float t = 1.0f - 2.0f/(e + 1.0f);
  return copysignf(t, x);
}
__device__ inline unsigned pack_bf16(float a, float b) {
  union { float f; unsigned u; } ua, ub; ua.f = a; ub.f = b;
  unsigned lo = (ua.u + 0x7fffu + ((ua.u >> 16) & 1u)) >> 16;
  unsigned hi = (ub.u + 0x7fffu + ((ub.u >> 16) & 1u)) & 0xffff0000u;
  return (lo & 0xffffu) | hi;
}
__device__ inline float bf_lo(unsigned p) { union { unsigned u; float f; } c; c.u = p << 16; return c.f; }
__device__ inline float bf_hi(unsigned p) { union { unsigned u; float f; } c; c.u = p & 0xffff0000u; return c.f; }

__device__ inline void stg(float* p, float v) {
  __hip_atomic_store(p, v, __ATOMIC_RELAXED, __HIP_MEMORY_SCOPE_AGENT);
}
__device__ inline float ldg_f(const float* p) {
  return __hip_atomic_load(p, __ATOMIC_RELAXED, __HIP_MEMORY_SCOPE_AGENT);
}

// ---------------- row L2-norm: xs[m] = max(||X[m,:]||, 1e-6) ----------------
__global__ __launch_bounds__(256) void rownorm_kernel(
    const float* __restrict__ X, float* __restrict__ xs, int M, int K)
{
  int wave = threadIdx.x >> 6, lane = threadIdx.x & 63;
  int m = blockIdx.x*4 + wave;
  if (m >= M) return;
  const float* row = X + (size_t)m*K;
  float acc = 0.f;
  for (int k = lane; k < K; k += 64) { float v = row[k]; acc += v*v; }
  acc = wave_sum(acc);
  if (lane == 0) xs[m] = fmaxf(sqrtf(acc), 1e-6f);
}

// ---------------- out init: out[b,t,c] = head_b[c] ----------------
__global__ __launch_bounds__(256) void initout_kernel(
    float* __restrict__ out, const float* __restrict__ head_b)
{
  int i4 = blockIdx.x*256 + threadIdx.x;         // float4 index
  float4 v = ((const float4*)head_b)[i4 & 15];   // 64 floats = 16 float4, repeats
  ((float4*)out)[i4] = v;
}

// ---------------- fused cell-1 recurrence + head ----------------
// 256 WGs = 32 batches x 8 slices of 64 rows. ONE flag-wave per step.
// Critical path per step: spin(8 flags) -> gather g/pb/be/ns -> error ->
// surprise -> err_eff -> h update -> C1 partials(t+1) -> stores -> flag(t+1).
// Everything feats-only (be0, pb=B1-col partials, norm, head matvec) runs in
// the SHADOW after the flag store, overlapping flag propagation latency.
__global__ __launch_bounds__(256, 1) void recur_kernel(
    const float* __restrict__ feats,
    const float* __restrict__ B0,
    const float* __restrict__ C1, const float* __restrict__ B1,
    const float* __restrict__ W1,
    const float* __restrict__ ltc,
    const float* __restrict__ tau0p, const float* __restrict__ gammap,
    const float* __restrict__ head_w,
    const float* __restrict__ xs0v,
    float* __restrict__ out,
    float* __restrict__ PG, float* __restrict__ PB,
    float* __restrict__ BE, float* __restrict__ NS,
    unsigned int* __restrict__ FL)
{
  const int wg = blockIdx.x;
  const int x = wg & 7, s = (wg >> 3) & 7, qq = wg >> 6;
  const int b = x*4 + qq;        // 8 slices of batch b share blockIdx%8 (XCD heuristic)
  const int row0 = s*64;
  const int tid = threadIdx.x;
  const int r = tid >> 2, kc = tid & 3;
  const int wid = tid >> 6, lane = tid & 63;

  __shared__ float b0_s[64*84];    // B0 slice, padded stride 84
  __shared__ float whh_s[64*68];   // head_w[c][row0+j]      (h half), stride 68
  __shared__ float whb_s[64*68];   // head_w[c][512+row0+j]  (be1 half)
  __shared__ float er_s[512];
  __shared__ float ft_s[80];
  __shared__ float h_s[64];
  __shared__ float bo_s[64];
  __shared__ float bv_s[64];
  __shared__ float a0_s[64];
  __shared__ float red_s[4], red2_s[4];

  // ---- static weights into registers ----
  float c1c[128];    // C1 column-slice: c1c[j*64+k] = C1[tid+j*256][row0+k]
  unsigned b1p[64];  // B1 column-slice, bf16-packed pairs
  float w1r[128];    // W1 row-slice, bank-staggered float4 order
  #pragma unroll
  for (int j = 0; j < 2; j++) {
    const float* src = C1 + (size_t)(tid + j*256)*512 + row0;
    #pragma unroll
    for (int k4 = 0; k4 < 16; k4++) {
      float4 v = *(const float4*)(src + 4*k4);
      c1c[j*64+4*k4]=v.x; c1c[j*64+4*k4+1]=v.y; c1c[j*64+4*k4+2]=v.z; c1c[j*64+4*k4+3]=v.w;
    }
  }
  #pragma unroll
  for (int j = 0; j < 2; j++) {
    const float* src = B1 + (size_t)(tid + j*256)*512 + row0;
    #pragma unroll
    for (int k4 = 0; k4 < 16; k4++) {
      float4 v = *(const float4*)(src + 4*k4);
      b1p[j*32+2*k4]   = pack_bf16(v.x, v.y);
      b1p[j*32+2*k4+1] = pack_bf16(v.z, v.w);
    }
  }
  {
    const float* src = W1 + (size_t)(row0 + r)*512;
    #pragma unroll
    for (int j4 = 0; j4 < 32; j4++) {
      const int f = kc*32 + ((j4 + kc) & 31);
      float4 v = *(const float4*)(src + 4*f);
      w1r[4*j4]=v.x; w1r[4*j4+1]=v.y; w1r[4*j4+2]=v.z; w1r[4*j4+3]=v.w;
    }
  }
  for (int i = tid; i < 5120; i += 256) {
    int rr = i/80, kk = i - rr*80;
    b0_s[rr*84 + kk] = B0[(size_t)(row0+rr)*80 + kk];
  }
  for (int i = tid; i < 4096; i += 256) {
    int c = i >> 6, j = i & 63;
    whh_s[c*68+j] = head_w[(size_t)c*1024 + row0 + j];
    whb_s[c*68+j] = head_w[(size_t)c*1024 + 512 + row0 + j];
  }
  if (tid < 64) {
    float xv = ltc[row0 + tid];
    float spl = (xv > 20.f) ? xv : log1pf(__expf(xv));
    a0_s[tid] = 0.1f / (1.0f + spl);
    h_s[tid] = 0.f;
  }
  const float tau0v = *tau0p, gmv = *gammap;
  unsigned int* flb = FL + b*32;    // 8 flags per batch, 128B-padded
  __syncthreads();

  // persistent shadow regs: the feats-only exchange set for the NEXT store
  float bev = 0.f, pb0 = 0.f, pb1 = 0.f, nsv = 0.f;

  // shadow(tt): compute be0 slice, ||be0||^2 partial, B1-col partials for step tt.
  // Depends only on feats -> runs off the critical path.
  auto shadow = [&](int tt) {
    const size_t bt_ = (size_t)b*SEQT + tt;
    if (tid < 80) ft_s[tid] = feats[bt_*80 + tid];
    const float rxs0_ = 1.0f / xs0v[bt_];
    __syncthreads();
    float a_ = 0.f;
    #pragma unroll
    for (int j4 = 0; j4 < 5; j4++) {
      float4 bw = *(const float4*)(b0_s + r*84 + kc*20 + 4*j4);
      float4 fv = *(const float4*)(ft_s + kc*20 + 4*j4);
      a_ += bw.x*fv.x + bw.y*fv.y + bw.z*fv.z + bw.w*fv.w;
    }
    a_ += __shfl_xor(a_, 1, 64); a_ += __shfl_xor(a_, 2, 64);
    bev = a_ * rxs0_;                 // all 4 lanes of row r hold it
    if (kc == 0) bo_s[r] = bev;
    float sq_ = 0.25f*bev*bev;        // each row counted 4x -> 0.25
    sq_ = wave_sum(sq_);
    if (lane == 0) red_s[wid] = sq_;
    __syncthreads();                  // bo_s, red_s ready
    nsv = red_s[0]+red_s[1]+red_s[2]+red_s[3];
    float p0a = 0.f, p1a = 0.f;
    #pragma unroll
    for (int k4 = 0; k4 < 16; k4++) {
      float4 ov = *(const float4*)(bo_s + 4*k4);
      unsigned p0 = b1p[2*k4], p1 = b1p[2*k4+1];
      unsigned q0 = b1p[32+2*k4], q1 = b1p[32+2*k4+1];
      p0a += bf_lo(p0)*ov.x + bf_hi(p0)*ov.y + bf_lo(p1)*ov.z + bf_hi(p1)*ov.w;
      p1a += bf_lo(q0)*ov.x + bf_hi(q0)*ov.y + bf_lo(q1)*ov.z + bf_hi(q1)*ov.w;
    }
    pb0 = p0a; pb1 = p1a;
  };

  // ---- prologue: exchange set for t=0 (g-partials = 0 since h=0), flag=1 ----
  shadow(0);
  {
    float* PGw = PG + (((size_t)0*BATCHN + b)*8 + s)*512;
    float* PBw = PB + (((size_t)0*BATCHN + b)*8 + s)*512;
    stg(&PGw[tid], 0.f); stg(&PGw[tid+256], 0.f);
    stg(&PBw[tid], pb0); stg(&PBw[tid+256], pb1);
    if (kc == 0) stg(&BE[((size_t)0*BATCHN + b)*512 + row0 + r], bev);
    if (tid == 0) stg(&NS[((size_t)0*BATCHN + b)*8 + s], nsv);
  }
  __syncthreads();   // all waves drain vmcnt before barrier -> stores visible
  if (tid == 0)
    __hip_atomic_store(&flb[s], 1u, __ATOMIC_RELEASE, __HIP_MEMORY_SCOPE_AGENT);
  shadow(1);         // set for t=1, stored at end of iteration t=0

  for (int t = 0; t < SEQT; ++t) {
    const int par = t & 1;

    // ---- spin: all 8 flags >= t+1 (all waves poll; >= because producers
    //      may already be one step ahead — equality would deadlock) ----
    {
      const unsigned tgt = (unsigned)(t + 1);
      u64* f64 = (u64*)flb;
      unsigned guard = 0;
      for (;;) {
        u64 q0 = __hip_atomic_load(&f64[0], __ATOMIC_RELAXED, __HIP_MEMORY_SCOPE_AGENT);
        u64 q1 = __hip_atomic_load(&f64[1], __ATOMIC_RELAXED, __HIP_MEMORY_SCOPE_AGENT);
        u64 q2 = __hip_atomic_load(&f64[2], __ATOMIC_RELAXED, __HIP_MEMORY_SCOPE_AGENT);
        u64 q3 = __hip_atomic_load(&f64[3], __ATOMIC_RELAXED, __HIP_MEMORY_SCOPE_AGENT);
        unsigned m0 = (unsigned)q0 < (unsigned)(q0>>32) ? (unsigned)q0 : (unsigned)(q0>>32);
        unsigned m1 = (unsigned)q1 < (unsigned)(q1>>32) ? (unsigned)q1 : (unsigned)(q1>>32);
        unsigned m2 = (unsigned)q2 < (unsigned)(q2>>32) ? (unsigned)q2 : (unsigned)(q2>>32);
        unsigned m3 = (unsigned)q3 < (unsigned)(q3>>32) ? (unsigned)q3 : (unsigned)(q3>>32);
        unsigned ma = m0 < m1 ? m0 : m1;
        unsigned mb = m2 < m3 ? m2 : m3;
        if ((ma < mb ? ma : mb) >= tgt) break;
        if (++guard > (1u<<24)) break;   // safety bail: wrong answer > hang
      }
      // acquire fence: keeps the data gathers below from hoisting above the spin
      (void)__hip_atomic_load(&flb[0], __ATOMIC_ACQUIRE, __HIP_MEMORY_SCOPE_AGENT);
    }

    // ---- gather ----
    const float* PGr = PG + ((size_t)par*BATCHN + b)*8*512;
    const float* PBr = PB + ((size_t)par*BATCHN + b)*8*512;
    const float* BEb = BE + ((size_t)par*BATCHN + b)*512;
    const float* NSb = NS + ((size_t)par*BATCHN + b)*8;

    float gp0 = 0.f, gp1 = 0.f;
    #pragma unroll
    for (int s2 = 0; s2 < 8; s2++) {
      gp0 += ldg_f(&PGr[s2*512 + tid]);
      gp1 += ldg_f(&PGr[s2*512 + tid+256]);
    }
    float xsq = 0.f;
    #pragma unroll
    for (int s2 = 0; s2 < 8; s2++) xsq += ldg_f(&NSb[s2]);
    const float bea = ldg_f(&BEb[tid]);
    const float beb = ldg_f(&BEb[tid+256]);
    float pbv = ldg_f(&PBr[(2*kc)*512 + row0 + r])
              + ldg_f(&PBr[(2*kc+1)*512 + row0 + r]);

    const float xs1 = fmaxf(sqrtf(xsq), 1e-6f);
    const float rxs1 = 1.0f / xs1;
    const float e0 = bea - xs1*ftanh(gp0);
    const float e1 = beb - xs1*ftanh(gp1);
    er_s[tid] = e0; er_s[tid+256] = e1;
    float es = wave_sum(e0*e0 + e1*e1);
    if (lane == 0) red2_s[wid] = es;
    pbv += __shfl_xor(pbv, 1, 64); pbv += __shfl_xor(pbv, 2, 64);
    const float be1v = pbv * rxs1;   // x_norm clip is a no-op: |be0_k| <= ||be0||
    __syncthreads();                 // er_s, red2_s ready
    if (kc == 0) bv_s[r] = be1v;     // after barrier: head(t-1) readers are done

    const float rel = fminf(sqrtf(red2_s[0]+red2_s[1]+red2_s[2]+red2_s[3]) * rxs1, 4.0f);
    const float sp = 1.0f/(1.0f + __expf(-(rel - tau0v)/gmv));

    // ---- err_eff row-slice matvec (bank-staggered er_s reads) ----
    float ee = 0.f;
    #pragma unroll
    for (int j4 = 0; j4 < 32; j4++) {
      const int f = kc*32 + ((j4 + kc) & 31);
      float4 ev = *(const float4*)(er_s + 4*f);
      ee += w1r[4*j4]*ev.x + w1r[4*j4+1]*ev.y + w1r[4*j4+2]*ev.z + w1r[4*j4+3]*ev.w;
    }
    ee += __shfl_xor(ee, 1, 64); ee += __shfl_xor(ee, 2, 64);

    const float hold = h_s[r];
    const float ih = 0.2f*hold + 0.6f*be1v + 0.2f*sp*ee;
    const float th = ftanh(ih);
    const float hn = hold + a0_s[r]*(1.0f + sp)*(th - hold);
    if (kc == 0) h_s[r] = hn;
    __syncthreads();                 // h_s new ready

    // ---- store-phase: C1 partials for t+1 from fresh h, plus the shadow
    //      set (be0/pb/ns for t+1) computed last iteration; then flag ----
    if (t < SEQT-1) {
      float pg0 = 0.f, pg1 = 0.f;
      #pragma unroll
      for (int k4 = 0; k4 < 16; k4++) {
        float4 hv = *(const float4*)(h_s + 4*k4);
        pg0 += c1c[4*k4]*hv.x + c1c[4*k4+1]*hv.y + c1c[4*k4+2]*hv.z + c1c[4*k4+3]*hv.w;
        pg1 += c1c[64+4*k4]*hv.x + c1c[64+4*k4+1]*hv.y + c1c[64+4*k4+2]*hv.z + c1c[64+4*k4+3]*hv.w;
      }
      const int pr = par ^ 1;
      float* PGw = PG + (((size_t)pr*BATCHN + b)*8 + s)*512;
      float* PBw = PB + (((size_t)pr*BATCHN + b)*8 + s)*512;
      stg(&PGw[tid], pg0); stg(&PGw[tid+256], pg1);
      stg(&PBw[tid], pb0); stg(&PBw[tid+256], pb1);
      if (kc == 0) stg(&BE[((size_t)pr*BATCHN + b)*512 + row0 + r], bev);
      if (tid == 0) stg(&NS[((size_t)pr*BATCHN + b)*8 + s], nsv);
      __syncthreads();               // drain all waves' stores before flag
      if (tid == 0)
        __hip_atomic_store(&flb[s], (unsigned)(t+2), __ATOMIC_RELEASE, __HIP_MEMORY_SCOPE_AGENT);
    }

    // ---- SHADOW region (overlaps flag propagation to other WGs) ----
    // head: out[b,t,c] += sum_{j in slice} h[j]*whh[c,j] + be1[j]*whb[c,j]
    {
      const size_t bt = (size_t)b*SEQT + t;
      const int c = r; const int j0 = kc*16;
      float hacc = 0.f;
      #pragma unroll
      for (int j4 = 0; j4 < 4; j4++) {
        float4 hv4 = *(const float4*)(h_s  + j0 + 4*j4);
        float4 bv4 = *(const float4*)(bv_s + j0 + 4*j4);
        float4 wh  = *(const float4*)(whh_s + c*68 + j0 + 4*j4);
        float4 wb  = *(const float4*)(whb_s + c*68 + j0 + 4*j4);
        hacc += hv4.x*wh.x + hv4.y*wh.y + hv4.z*wh.z + hv4.w*wh.w
              + bv4.x*wb.x + bv4.y*wb.y + bv4.z*wb.z + bv4.w*wb.w;
      }
      hacc += __shfl_xor(hacc, 1, 64); hacc += __shfl_xor(hacc, 2, 64);
      if (kc == 0) atomicAdd(&out[bt*64 + c], hacc);
    }
    if (t < SEQT-2) shadow(t+2);     // feats-only set for the next store-phase
    // no end-of-loop sync needed: next iteration's LDS writes are ordered
    // behind this iteration's barriers (er_s sync / h_s sync / store sync)
  }
}

extern "C" void kernel_launch(void* const* d_in, const int* in_sizes, int n_in,
                              void* d_out, int out_size, void* d_ws, size_t ws_size,
                              hipStream_t stream)
{
  (void)in_sizes; (void)n_in; (void)out_size;
  const float* feats  = (const float*)d_in[0];
  const float* B0     = (const float*)d_in[2];
  const float* C1     = (const float*)d_in[7];
  const float* B1     = (const float*)d_in[8];
  const float* W1     = (const float*)d_in[9];
  const float* tau0_1 = (const float*)d_in[10];
  const float* gamma1 = (const float*)d_in[11];
  const float* ltc1   = (const float*)d_in[12];
  const float* head_w = (const float*)d_in[13];
  const float* head_b = (const float*)d_in[14];
  float* out = (float*)d_out;

  // ws layout (fp32 unless noted): PG[2][32][8][512] | PB[2][32][8][512] |
  //   BE[2][32][512] | NS[2][32][8] | xs0[65536] | FL[32*32 u32]   (~2.5 MB)
  float* PG  = (float*)d_ws;
  float* PB  = PG + (size_t)2*BATCHN*8*HIDN;
  float* BE  = PB + (size_t)2*BATCHN*8*HIDN;
  float* NS  = BE + (size_t)2*BATCHN*HIDN;
  float* xs0 = NS + (size_t)2*BATCHN*8;
  unsigned int* FL = (unsigned int*)(xs0 + BTROWS);
  size_t needed = (size_t)((char*)(FL + BATCHN*32) - (char*)d_ws);
  if (ws_size < needed) return;   // ~2.5 MB — comfortably small

  rownorm_kernel<<<BTROWS/4, 256, 0, stream>>>(feats, xs0, BTROWS, NMELS);
  initout_kernel<<<(BTROWS*NCLSN/4)/256, 256, 0, stream>>>(out, head_b);
  hipMemsetAsync(FL, 0, BATCHN*32*sizeof(unsigned int), stream);

  void* args[] = { (void*)&feats, (void*)&B0, (void*)&C1, (void*)&B1, (void*)&W1,
                   (void*)&ltc1, (void*)&tau0_1, (void*)&gamma1, (void*)&head_w,
                   (void*)&xs0, (void*)&out,
                   (void*)&PG, (void*)&PB, (void*)&BE, (void*)&NS, (void*)&FL };
  hipError_t e = hipLaunchCooperativeKernel((void*)recur_kernel, dim3(256), dim3(256),
                                            args, 0, stream);
  if (e != hipSuccess) {
    recur_kernel<<<256, 256, 0, stream>>>(feats, B0, C1, B1, W1, ltc1, tau0_1, gamma1,
                                          head_w, xs0, out, PG, PB, BE, NS, FL);
  }
}

// Round 2
// 12087.481 us; speedup vs baseline: 2.2543x; 2.2543x over previous
//
#include <hip/hip_runtime.h>
#include <math.h>

#define BATCHN 32
#define SEQT   2048
#define NMELS  80
#define HIDN   512
#define NCLSN  64
#define BTROWS (BATCHN*SEQT)   // 65536

typedef unsigned long long u64;

__device__ inline float wave_sum(float v) {
  #pragma unroll
  for (int o = 32; o > 0; o >>= 1) v += __shfl_xor(v, o, 64);
  return v;
}
__device__ inline float ftanh(float x) {
  float ax = fabsf(x);
  float e = __expf(2.0f*ax);
  float t = 1.0f - 2.0f/(e + 1.0f);
  return copysignf(t, x);
}
__device__ inline unsigned pack_bf16(float a, float b) {
  union { float f; unsigned u; } ua, ub; ua.f = a; ub.f = b;
  unsigned lo = (ua.u + 0x7fffu + ((ua.u >> 16) & 1u)) >> 16;
  unsigned hi = (ub.u + 0x7fffu + ((ub.u >> 16) & 1u)) & 0xffff0000u;
  return (lo & 0xffffu) | hi;
}
__device__ inline float bf_lo(unsigned p) { union { unsigned u; float f; } c; c.u = p << 16; return c.f; }
__device__ inline float bf_hi(unsigned p) { union { unsigned u; float f; } c; c.u = p & 0xffff0000u; return c.f; }

// epoch-stamped exchange word: {epoch (hi32) | f32 bits (lo32)}
__device__ inline u64 pk64(float v, unsigned ep) {
  union { float f; unsigned u; } c; c.f = v;
  return ((u64)ep << 32) | (u64)c.u;
}
__device__ inline float lo32f(u64 q) {
  union { unsigned u; float f; } c; c.u = (unsigned)q; return c.f;
}
__device__ inline void st64(u64* p, u64 v) {
  __hip_atomic_store(p, v, __ATOMIC_RELAXED, __HIP_MEMORY_SCOPE_AGENT);
}
__device__ inline u64 ld64(const u64* p) {
  return __hip_atomic_load(p, __ATOMIC_RELAXED, __HIP_MEMORY_SCOPE_AGENT);
}

// ---------------- row L2-norm: xs[m] = max(||X[m,:]||, 1e-6) ----------------
__global__ __launch_bounds__(256) void rownorm_kernel(
    const float* __restrict__ X, float* __restrict__ xs, int M, int K)
{
  int wave = threadIdx.x >> 6, lane = threadIdx.x & 63;
  int m = blockIdx.x*4 + wave;
  if (m >= M) return;
  const float* row = X + (size_t)m*K;
  float acc = 0.f;
  for (int k = lane; k < K; k += 64) { float v = row[k]; acc += v*v; }
  acc = wave_sum(acc);
  if (lane == 0) xs[m] = fmaxf(sqrtf(acc), 1e-6f);
}

// ---------------- out init: out[b,t,c] = head_b[c] ----------------
__global__ __launch_bounds__(256) void initout_kernel(
    float* __restrict__ out, const float* __restrict__ head_b)
{
  int i4 = blockIdx.x*256 + threadIdx.x;         // float4 index
  float4 v = ((const float4*)head_b)[i4 & 15];   // 64 floats = 16 float4, repeats
  ((float4*)out)[i4] = v;
}

// ---------------- fused cell-1 recurrence + head ----------------
// 256 WGs = 32 batches x 8 slices of 64 rows.
// Exchange uses EPOCH-STAMPED u64 words (no flags, no store-drain, no spin):
// the consumer's gather IS the poll — reload until every word carries epoch
// t+1. Per-word 8B atomicity makes store ordering irrelevant; 2-deep parity
// buffering guarantees a slot is only overwritten (epoch t+3) after every WG
// finished reading epoch t+1. This removes ~3 of the ~5 serialized
// coherence-point round trips per step that dominated the old critical path.
__global__ __launch_bounds__(256, 1) void recur_kernel(
    const float* __restrict__ feats,
    const float* __restrict__ B0,
    const float* __restrict__ C1, const float* __restrict__ B1,
    const float* __restrict__ W1,
    const float* __restrict__ ltc,
    const float* __restrict__ tau0p, const float* __restrict__ gammap,
    const float* __restrict__ head_w,
    const float* __restrict__ xs0v,
    float* __restrict__ out,
    u64* __restrict__ PG, u64* __restrict__ PB,
    u64* __restrict__ BE, u64* __restrict__ NS)
{
  const int wg = blockIdx.x;
  const int x = wg & 7, s = (wg >> 3) & 7, qq = wg >> 6;
  const int b = x*4 + qq;        // 8 slices of batch b share blockIdx%8 (XCD heuristic)
  const int row0 = s*64;
  const int tid = threadIdx.x;
  const int r = tid >> 2, kc = tid & 3;
  const int wid = tid >> 6, lane = tid & 63;

  __shared__ float b0_s[64*84];    // B0 slice, padded stride 84
  __shared__ float whh_s[64*68];   // head_w[c][row0+j]      (h half), stride 68
  __shared__ float whb_s[64*68];   // head_w[c][512+row0+j]  (be1 half)
  __shared__ float er_s[512];
  __shared__ float ft_s[80];
  __shared__ float h_s[64];
  __shared__ float bo_s[64];
  __shared__ float bv_s[64];
  __shared__ float a0_s[64];
  __shared__ float red_s[4], red2_s[4];

  // ---- static weights into registers ----
  float c1c[128];    // C1 column-slice: c1c[j*64+k] = C1[tid+j*256][row0+k]
  unsigned b1p[64];  // B1 column-slice, bf16-packed pairs
  float w1r[128];    // W1 row-slice, bank-staggered float4 order
  #pragma unroll
  for (int j = 0; j < 2; j++) {
    const float* src = C1 + (size_t)(tid + j*256)*512 + row0;
    #pragma unroll
    for (int k4 = 0; k4 < 16; k4++) {
      float4 v = *(const float4*)(src + 4*k4);
      c1c[j*64+4*k4]=v.x; c1c[j*64+4*k4+1]=v.y; c1c[j*64+4*k4+2]=v.z; c1c[j*64+4*k4+3]=v.w;
    }
  }
  #pragma unroll
  for (int j = 0; j < 2; j++) {
    const float* src = B1 + (size_t)(tid + j*256)*512 + row0;
    #pragma unroll
    for (int k4 = 0; k4 < 16; k4++) {
      float4 v = *(const float4*)(src + 4*k4);
      b1p[j*32+2*k4]   = pack_bf16(v.x, v.y);
      b1p[j*32+2*k4+1] = pack_bf16(v.z, v.w);
    }
  }
  {
    const float* src = W1 + (size_t)(row0 + r)*512;
    #pragma unroll
    for (int j4 = 0; j4 < 32; j4++) {
      const int f = kc*32 + ((j4 + kc) & 31);
      float4 v = *(const float4*)(src + 4*f);
      w1r[4*j4]=v.x; w1r[4*j4+1]=v.y; w1r[4*j4+2]=v.z; w1r[4*j4+3]=v.w;
    }
  }
  for (int i = tid; i < 5120; i += 256) {
    int rr = i/80, kk = i - rr*80;
    b0_s[rr*84 + kk] = B0[(size_t)(row0+rr)*80 + kk];
  }
  for (int i = tid; i < 4096; i += 256) {
    int c = i >> 6, j = i & 63;
    whh_s[c*68+j] = head_w[(size_t)c*1024 + row0 + j];
    whb_s[c*68+j] = head_w[(size_t)c*1024 + 512 + row0 + j];
  }
  if (tid < 64) {
    float xv = ltc[row0 + tid];
    float spl = (xv > 20.f) ? xv : log1pf(__expf(xv));
    a0_s[tid] = 0.1f / (1.0f + spl);
    h_s[tid] = 0.f;
  }
  const float tau0v = *tau0p, gmv = *gammap;
  __syncthreads();

  // persistent shadow regs: the feats-only exchange set for the NEXT store
  float bev = 0.f, pb0 = 0.f, pb1 = 0.f, nsv = 0.f;

  // shadow: be0 slice, ||be0||^2 partial, B1-col partials from a staged feats
  // row (feats-only -> off the h-dependency critical path).
  auto shadow = [&](float ftv, float xsv) {
    if (tid < 80) ft_s[tid] = ftv;
    const float rxs0_ = 1.0f / xsv;
    __syncthreads();
    float a_ = 0.f;
    #pragma unroll
    for (int j4 = 0; j4 < 5; j4++) {
      float4 bw = *(const float4*)(b0_s + r*84 + kc*20 + 4*j4);
      float4 fv = *(const float4*)(ft_s + kc*20 + 4*j4);
      a_ += bw.x*fv.x + bw.y*fv.y + bw.z*fv.z + bw.w*fv.w;
    }
    a_ += __shfl_xor(a_, 1, 64); a_ += __shfl_xor(a_, 2, 64);
    bev = a_ * rxs0_;                 // all 4 lanes of row r hold it
    if (kc == 0) bo_s[r] = bev;
    float sq_ = 0.25f*bev*bev;        // each row counted 4x -> 0.25
    sq_ = wave_sum(sq_);
    if (lane == 0) red_s[wid] = sq_;
    __syncthreads();                  // bo_s, red_s ready
    nsv = red_s[0]+red_s[1]+red_s[2]+red_s[3];
    float p0a = 0.f, p1a = 0.f;
    #pragma unroll
    for (int k4 = 0; k4 < 16; k4++) {
      float4 ov = *(const float4*)(bo_s + 4*k4);
      unsigned p0 = b1p[2*k4], p1 = b1p[2*k4+1];
      unsigned q0 = b1p[32+2*k4], q1 = b1p[32+2*k4+1];
      p0a += bf_lo(p0)*ov.x + bf_hi(p0)*ov.y + bf_lo(p1)*ov.z + bf_hi(p1)*ov.w;
      p1a += bf_lo(q0)*ov.x + bf_hi(q0)*ov.y + bf_lo(q1)*ov.z + bf_hi(q1)*ov.w;
    }
    pb0 = p0a; pb1 = p1a;
  };

  // ---- prologue: post epoch-1 set for t=0 (g-partials = 0 since h=0) ----
  {
    const size_t bt0 = (size_t)b*SEQT;
    float ftv = (tid < 80) ? feats[bt0*80 + tid] : 0.f;
    shadow(ftv, xs0v[bt0]);
    u64* PGw = PG + (((size_t)0*BATCHN + b)*8 + s)*512;
    u64* PBw = PB + (((size_t)0*BATCHN + b)*8 + s)*512;
    st64(&PGw[tid],     pk64(0.f, 1u)); st64(&PGw[tid+256], pk64(0.f, 1u));
    st64(&PBw[tid],     pk64(pb0, 1u)); st64(&PBw[tid+256], pk64(pb1, 1u));
    if (kc == 0)  st64(&BE[((size_t)0*BATCHN + b)*512 + row0 + r], pk64(bev, 1u));
    if (tid == 0) st64(&NS[((size_t)0*BATCHN + b)*8 + s], pk64(nsv, 1u));
  }
  // shadow set for t=1 (posted during iteration t=0's store-phase)
  {
    const size_t bt1 = (size_t)b*SEQT + 1;
    float ftv = (tid < 80) ? feats[bt1*80 + tid] : 0.f;
    shadow(ftv, xs0v[bt1]);
  }

  for (int t = 0; t < SEQT; ++t) {
    const int par = t & 1;
    const unsigned ep = (unsigned)(t + 1);

    // ---- prefetch feats(t+2) into regs (completes during the gather) ----
    float ftn = 0.f, xsn = 1.f;
    if (t < SEQT-2) {
      const size_t btn = (size_t)b*SEQT + (t+2);
      if (tid < 80) ftn = feats[btn*80 + tid];
      xsn = xs0v[btn];
    }

    // ---- gather-poll: reload until every word carries epoch t+1 ----
    const u64* PGr = PG + ((size_t)par*BATCHN + b)*8*512;
    const u64* PBr = PB + ((size_t)par*BATCHN + b)*8*512;
    const u64* BEb = BE + ((size_t)par*BATCHN + b)*512;
    const u64* NSb = NS + ((size_t)par*BATCHN + b)*8;

    float gp0, gp1, xsq, bea, beb, pbv;
    {
      unsigned g = 0;
      for (;;) {
        bool ok = true;
        float a0 = 0.f, a1 = 0.f;
        #pragma unroll
        for (int s2 = 0; s2 < 8; s2++) {
          u64 q  = ld64(&PGr[s2*512 + tid]);
          u64 q2 = ld64(&PGr[s2*512 + tid+256]);
          ok &= ((unsigned)(q  >> 32) == ep);
          ok &= ((unsigned)(q2 >> 32) == ep);
          a0 += lo32f(q); a1 += lo32f(q2);
        }
        float xq = 0.f;
        #pragma unroll
        for (int s2 = 0; s2 < 8; s2++) {
          u64 q = ld64(&NSb[s2]);
          ok &= ((unsigned)(q >> 32) == ep);
          xq += lo32f(q);
        }
        u64 qa  = ld64(&BEb[tid]);
        u64 qb  = ld64(&BEb[tid+256]);
        u64 qp  = ld64(&PBr[(2*kc)*512   + row0 + r]);
        u64 qp2 = ld64(&PBr[(2*kc+1)*512 + row0 + r]);
        ok &= ((unsigned)(qa  >> 32) == ep);
        ok &= ((unsigned)(qb  >> 32) == ep);
        ok &= ((unsigned)(qp  >> 32) == ep);
        ok &= ((unsigned)(qp2 >> 32) == ep);
        ++g;
        if (ok || g > (1u<<18)) {    // bail: wrong answer > hang
          gp0 = a0; gp1 = a1; xsq = xq;
          bea = lo32f(qa); beb = lo32f(qb);
          pbv = lo32f(qp) + lo32f(qp2);
          break;
        }
      }
    }

    const float xs1 = fmaxf(sqrtf(xsq), 1e-6f);
    const float rxs1 = 1.0f / xs1;
    const float e0 = bea - xs1*ftanh(gp0);
    const float e1 = beb - xs1*ftanh(gp1);
    er_s[tid] = e0; er_s[tid+256] = e1;
    float es = wave_sum(e0*e0 + e1*e1);
    if (lane == 0) red2_s[wid] = es;
    pbv += __shfl_xor(pbv, 1, 64); pbv += __shfl_xor(pbv, 2, 64);
    const float be1v = pbv * rxs1;   // x_norm clip is a no-op: |be0_k| <= ||be0||
    __syncthreads();                 // er_s, red2_s ready
    if (kc == 0) bv_s[r] = be1v;     // after barrier: head(t-1) readers are done

    const float rel = fminf(sqrtf(red2_s[0]+red2_s[1]+red2_s[2]+red2_s[3]) * rxs1, 4.0f);
    const float sp = 1.0f/(1.0f + __expf(-(rel - tau0v)/gmv));

    // ---- err_eff row-slice matvec (bank-staggered er_s reads) ----
    float ee = 0.f;
    #pragma unroll
    for (int j4 = 0; j4 < 32; j4++) {
      const int f = kc*32 + ((j4 + kc) & 31);
      float4 ev = *(const float4*)(er_s + 4*f);
      ee += w1r[4*j4]*ev.x + w1r[4*j4+1]*ev.y + w1r[4*j4+2]*ev.z + w1r[4*j4+3]*ev.w;
    }
    ee += __shfl_xor(ee, 1, 64); ee += __shfl_xor(ee, 2, 64);

    const float hold = h_s[r];
    const float ih = 0.2f*hold + 0.6f*be1v + 0.2f*sp*ee;
    const float th = ftanh(ih);
    const float hn = hold + a0_s[r]*(1.0f + sp)*(th - hold);
    if (kc == 0) h_s[r] = hn;
    __syncthreads();                 // h_s new ready

    // ---- store-phase: post epoch t+2 (C1 partials from fresh h + the
    //      feats-only set computed by last iteration's shadow) ----
    if (t < SEQT-1) {
      float pg0 = 0.f, pg1 = 0.f;
      #pragma unroll
      for (int k4 = 0; k4 < 16; k4++) {
        float4 hv = *(const float4*)(h_s + 4*k4);
        pg0 += c1c[4*k4]*hv.x + c1c[4*k4+1]*hv.y + c1c[4*k4+2]*hv.z + c1c[4*k4+3]*hv.w;
        pg1 += c1c[64+4*k4]*hv.x + c1c[64+4*k4+1]*hv.y + c1c[64+4*k4+2]*hv.z + c1c[64+4*k4+3]*hv.w;
      }
      const int pr = par ^ 1;
      const unsigned ep2 = ep + 1u;
      u64* PGw = PG + (((size_t)pr*BATCHN + b)*8 + s)*512;
      u64* PBw = PB + (((size_t)pr*BATCHN + b)*8 + s)*512;
      st64(&PGw[tid],     pk64(pg0, ep2)); st64(&PGw[tid+256], pk64(pg1, ep2));
      st64(&PBw[tid],     pk64(pb0, ep2)); st64(&PBw[tid+256], pk64(pb1, ep2));
      if (kc == 0)  st64(&BE[((size_t)pr*BATCHN + b)*512 + row0 + r], pk64(bev, ep2));
      if (tid == 0) st64(&NS[((size_t)pr*BATCHN + b)*8 + s], pk64(nsv, ep2));
      // no drain, no flag — the epoch rides with each word
    }

    // ---- SHADOW region (overlaps store visibility to other WGs) ----
    // head: out[b,t,c] += sum_{j in slice} h[j]*whh[c,j] + be1[j]*whb[c,j]
    {
      const size_t bt = (size_t)b*SEQT + t;
      const int c = r; const int j0 = kc*16;
      float hacc = 0.f;
      #pragma unroll
      for (int j4 = 0; j4 < 4; j4++) {
        float4 hv4 = *(const float4*)(h_s  + j0 + 4*j4);
        float4 bv4 = *(const float4*)(bv_s + j0 + 4*j4);
        float4 wh  = *(const float4*)(whh_s + c*68 + j0 + 4*j4);
        float4 wb  = *(const float4*)(whb_s + c*68 + j0 + 4*j4);
        hacc += hv4.x*wh.x + hv4.y*wh.y + hv4.z*wh.z + hv4.w*wh.w
              + bv4.x*wb.x + bv4.y*wb.y + bv4.z*wb.z + bv4.w*wb.w;
      }
      hacc += __shfl_xor(hacc, 1, 64); hacc += __shfl_xor(hacc, 2, 64);
      if (kc == 0) atomicAdd(&out[bt*64 + c], hacc);
    }
    if (t < SEQT-2) shadow(ftn, xsn);  // feats-only set for the next store-phase
    // no end-of-loop sync needed: next iteration's LDS writes are ordered
    // behind this iteration's barriers (er_s sync / h_s sync / shadow syncs)
  }
}

extern "C" void kernel_launch(void* const* d_in, const int* in_sizes, int n_in,
                              void* d_out, int out_size, void* d_ws, size_t ws_size,
                              hipStream_t stream)
{
  (void)in_sizes; (void)n_in; (void)out_size;
  const float* feats  = (const float*)d_in[0];
  const float* B0     = (const float*)d_in[2];
  const float* C1     = (const float*)d_in[7];
  const float* B1     = (const float*)d_in[8];
  const float* W1     = (const float*)d_in[9];
  const float* tau0_1 = (const float*)d_in[10];
  const float* gamma1 = (const float*)d_in[11];
  const float* ltc1   = (const float*)d_in[12];
  const float* head_w = (const float*)d_in[13];
  const float* head_b = (const float*)d_in[14];
  float* out = (float*)d_out;

  // ws layout: PG u64[2][32][8][512] | PB u64[2][32][8][512] |
  //   BE u64[2][32][512] | NS u64[2][32][8] | xs0 f32[65536]   (~4.7 MB)
  u64* PG  = (u64*)d_ws;
  u64* PB  = PG + (size_t)2*BATCHN*8*HIDN;
  u64* BE  = PB + (size_t)2*BATCHN*8*HIDN;
  u64* NS  = BE + (size_t)2*BATCHN*HIDN;
  float* xs0 = (float*)(NS + (size_t)2*BATCHN*8);
  size_t needed = (size_t)((char*)(xs0 + BTROWS) - (char*)d_ws);
  if (ws_size < needed) return;

  rownorm_kernel<<<BTROWS/4, 256, 0, stream>>>(feats, xs0, BTROWS, NMELS);
  initout_kernel<<<(BTROWS*NCLSN/4)/256, 256, 0, stream>>>(out, head_b);
  // zero epochs so stale words from a previous launch can never alias t+1
  hipMemsetAsync(PG, 0, (size_t)((char*)xs0 - (char*)PG), stream);

  void* args[] = { (void*)&feats, (void*)&B0, (void*)&C1, (void*)&B1, (void*)&W1,
                   (void*)&ltc1, (void*)&tau0_1, (void*)&gamma1, (void*)&head_w,
                   (void*)&xs0, (void*)&out,
                   (void*)&PG, (void*)&PB, (void*)&BE, (void*)&NS };
  hipError_t e = hipLaunchCooperativeKernel((void*)recur_kernel, dim3(256), dim3(256),
                                            args, 0, stream);
  if (e != hipSuccess) {
    recur_kernel<<<256, 256, 0, stream>>>(feats, B0, C1, B1, W1, ltc1, tau0_1, gamma1,
                                          head_w, xs0, out, PG, PB, BE, NS);
  }
}